// Round 2
// baseline (395.618 us; speedup 1.0000x reference)
//
#include <hip/hip_runtime.h>

typedef unsigned short u16;
typedef __attribute__((ext_vector_type(8))) short bf16x8;
typedef __attribute__((ext_vector_type(4))) float f32x4;
typedef __attribute__((ext_vector_type(4))) u16 u16x4;

constexpr int BATCH = 4096;
constexpr int SEQ   = 512;
constexpr int HID   = 64;

__device__ __forceinline__ float bf2f(u16 u) {
  union { unsigned int i; float f; } c; c.i = ((unsigned int)u) << 16; return c.f;
}
__device__ __forceinline__ u16 f2bf(float f) {
  union { float f; unsigned int i; } c; c.f = f;
  unsigned int u = c.i;
  u += 0x7fffu + ((u >> 16) & 1u);   // round-to-nearest-even (finite inputs only)
  return (u16)(u >> 16);
}
__device__ __forceinline__ float fast_tanh(float v) {
  float e = __expf(v + v);
  float r = __builtin_amdgcn_rcpf(e + 1.0f);
  return fmaf(-2.0f, r, 1.0f);       // 1 - 2/(e^{2x}+1); saturates at +-1
}

#define MFMA16(a, b, c) __builtin_amdgcn_mfma_f32_16x16x32_bf16(a, b, c, 0, 0, 0)

// ---- Prep kernel A: fp32 emb -> bf16(hi) table in ws (RNE). 4 elems/thread.
__global__ __launch_bounds__(256) void cvt_emb_kernel(
    const float4* __restrict__ src, u16x4* __restrict__ dst, int n4)
{
  int i = blockIdx.x * 256 + threadIdx.x;
  if (i < n4) {
    float4 v = src[i];
    u16x4 o;
    o.x = f2bf(v.x); o.y = f2bf(v.y); o.z = f2bf(v.z); o.w = f2bf(v.w);
    dst[i] = o;
  }
}

// ---- Prep kernel B: W_ih -> hi; W_hh -> hi + lo residual (bf16 pair ~ fp32).
__global__ __launch_bounds__(256) void cvt_w_kernel(
    const float* __restrict__ Wih, const float* __restrict__ Whh,
    u16* __restrict__ wih_hi, u16* __restrict__ whh_hi, u16* __restrict__ whh_lo)
{
  int i = blockIdx.x * 256 + threadIdx.x;   // 0..4095
  wih_hi[i] = f2bf(Wih[i]);
  float w = Whh[i];
  u16 hi = f2bf(w);
  whh_hi[i] = hi;
  whh_lo[i] = f2bf(w - bf2f(hi));
}

// ---- Kernel 1: fused embedding-gather + input projection + tanh-RNN scan.
// Grid: 256 blocks x 256 threads. Block bg owns batch rows [16bg, 16bg+16).
// Wave w (of 4) owns output features [16w, 16w+16).
// MFMA 16x16x32 bf16; C: col=lane&15 (feature), row=4*(lane>>4)+reg (batch).
// A: m=lane&15, k=8*(lane>>4)+j.  B: n=lane&15, k=8*(lane>>4)+j.
// h kept as bf16 hi+lo pair in XOR-swizzled, double-buffered LDS.
// h @ W_hh^T computed as hi*Whi + lo*Whi + hi*Wlo (fp32-grade), 6 MFMA + 2 for xp.
__global__ __launch_bounds__(256) void rnn_scan_kernel(
    const int* __restrict__ xx, const u16* __restrict__ emb_bf,
    const u16* __restrict__ wih_hi, const u16* __restrict__ whh_hi,
    const u16* __restrict__ whh_lo,
    const float* __restrict__ b_ih, const float* __restrict__ b_hh,
    float* __restrict__ hT /* [HID][BATCH] */)
{
  __shared__ u16 hbuf[2 * 2 * 16 * 64];   // [buf][hi/lo][m=16][chunk=8][elem=8]
  const int tid = threadIdx.x;
  const int w = tid >> 6;
  const int L = tid & 63;
  const int n = L & 15;
  const int q = L >> 4;
  const int R0 = blockIdx.x << 4;
  const int row  = R0 + n;                // this lane's gather row (A operand m=n)
  const int feat = (w << 4) + n;          // this lane's B-operand feature column

  // Constant B-fragments (weights) in registers. W[feat][k], k-contig 16B chunks.
  bf16x8 Bih0 = *(const bf16x8*)(wih_hi + feat * 64 +      8 * q);
  bf16x8 Bih1 = *(const bf16x8*)(wih_hi + feat * 64 + 32 + 8 * q);
  bf16x8 Bh0  = *(const bf16x8*)(whh_hi + feat * 64 +      8 * q);
  bf16x8 Bh1  = *(const bf16x8*)(whh_hi + feat * 64 + 32 + 8 * q);
  bf16x8 Bl0  = *(const bf16x8*)(whh_lo + feat * 64 +      8 * q);
  bf16x8 Bl1  = *(const bf16x8*)(whh_lo + feat * 64 + 32 + 8 * q);
  const float bias = b_ih[feat] + b_hh[feat];

  // LDS A-frag read offsets (u16 elems): row m=n, chunk c, XOR-swizzled by m&7.
  const int r0off = n * 64 + (((0 + q) ^ (n & 7)) << 3);
  const int r1off = n * 64 + (((4 + q) ^ (n & 7)) << 3);

  // Software pipeline: emb frags one step ahead, index two steps ahead.
  int idx_n;
  bf16x8 ae0, ae1;
  {
    int idx0 = xx[row * SEQ + 0];
    const u16* eb = emb_bf + idx0 * 64;
    ae0 = *(const bf16x8*)(eb +      8 * q);
    ae1 = *(const bf16x8*)(eb + 32 + 8 * q);
    idx_n = xx[row * SEQ + 1];
  }

  for (int s = 0; s < SEQ; ++s) {
    const int cur = s & 1;
    const int nxt = cur ^ 1;

    bf16x8 pe0 = ae0, pe1 = ae1;
    if (s + 1 < SEQ) {
      const u16* eb = emb_bf + idx_n * 64;
      pe0 = *(const bf16x8*)(eb +      8 * q);
      pe1 = *(const bf16x8*)(eb + 32 + 8 * q);
    }
    if (s + 2 < SEQ) idx_n = xx[row * SEQ + s + 2];

    f32x4 C1 = {bias, bias, bias, bias};
    C1 = MFMA16(ae0, Bih0, C1);           // xp (k = 0..31), no LDS dependency
    C1 = MFMA16(ae1, Bih1, C1);           // xp (k = 32..63)
    if (s > 0) {
      const u16* hb = hbuf + cur * 2048;
      bf16x8 ah0 = *(const bf16x8*)(hb + r0off);
      bf16x8 ah1 = *(const bf16x8*)(hb + r1off);
      bf16x8 al0 = *(const bf16x8*)(hb + 1024 + r0off);
      bf16x8 al1 = *(const bf16x8*)(hb + 1024 + r1off);
      f32x4 C2 = {0.f, 0.f, 0.f, 0.f};
      f32x4 C3 = {0.f, 0.f, 0.f, 0.f};
      C2 = MFMA16(ah0, Bh0, C2);          // h_hi * W_hi
      C3 = MFMA16(ah1, Bh1, C3);
      C2 = MFMA16(al0, Bh0, C2);          // h_lo * W_hi
      C3 = MFMA16(al1, Bh1, C3);
      C2 = MFMA16(ah0, Bl0, C2);          // h_hi * W_lo
      C3 = MFMA16(ah1, Bl1, C3);
      #pragma unroll
      for (int r = 0; r < 4; ++r) C1[r] += C2[r] + C3[r];
    }

    u16* wb = hbuf + nxt * 2048;
    #pragma unroll
    for (int r = 0; r < 4; ++r) {
      float t = fast_tanh(C1[r]);
      const int mw = (q << 2) + r;                     // batch row within group
      const int cw = ((w << 1) + (n >> 3)) ^ (mw & 7); // swizzled feature chunk
      const int off = mw * 64 + (cw << 3) + (n & 7);
      u16 hi = f2bf(t);
      wb[off] = hi;
      wb[1024 + off] = f2bf(t - bf2f(hi));
      if (s == SEQ - 1) hT[feat * BATCH + R0 + mw] = t;  // transposed h_n for BN
    }
    __syncthreads();   // writes(s) visible to reads(s+1); guards buffer swap
    ae0 = pe0; ae1 = pe1;
  }
}

// ---- Kernel 2: per-feature batch stats -> folded BN scale/shift (fp32).
__global__ __launch_bounds__(256) void bn_stats_kernel(
    const float* __restrict__ hT, const float* __restrict__ gamma,
    const float* __restrict__ beta, float* __restrict__ scale_shift)
{
  const int j = blockIdx.x;
  const float* v = hT + j * BATCH;
  float sum = 0.f, sq = 0.f;
  for (int i = threadIdx.x; i < BATCH; i += 256) {
    float t = v[i];
    sum += t;
    sq = fmaf(t, t, sq);
  }
  #pragma unroll
  for (int o = 32; o > 0; o >>= 1) {
    sum += __shfl_down(sum, o, 64);
    sq  += __shfl_down(sq,  o, 64);
  }
  __shared__ float s1[4], s2[4];
  const int wv = threadIdx.x >> 6;
  if ((threadIdx.x & 63) == 0) { s1[wv] = sum; s2[wv] = sq; }
  __syncthreads();
  if (threadIdx.x == 0) {
    float S1 = s1[0] + s1[1] + s1[2] + s1[3];
    float S2 = s2[0] + s2[1] + s2[2] + s2[3];
    float mean = S1 * (1.0f / BATCH);
    float var  = S2 * (1.0f / BATCH) - mean * mean;   // biased, matches reference
    float inv  = rsqrtf(var + 1e-5f);
    float sc   = gamma[j] * inv;
    scale_shift[j]      = sc;
    scale_shift[64 + j] = beta[j] - mean * sc;
  }
}

// ---- Kernel 3: logits = (h*scale + shift) @ W_fc^T + b_fc. fp32 out.
__global__ __launch_bounds__(256) void head_kernel(
    const float* __restrict__ hT, const float* __restrict__ scale_shift,
    const float* __restrict__ Wfc, const float* __restrict__ bfc,
    float* __restrict__ out)
{
  const int b = blockIdx.x * 256 + threadIdx.x;
  float acc[5];
  #pragma unroll
  for (int c = 0; c < 5; ++c) acc[c] = bfc[c];
  for (int j = 0; j < HID; ++j) {
    float hv  = hT[j * BATCH + b];                      // coalesced across lanes
    float hat = fmaf(hv, scale_shift[j], scale_shift[64 + j]);
    #pragma unroll
    for (int c = 0; c < 5; ++c) acc[c] = fmaf(hat, Wfc[c * 64 + j], acc[c]);
  }
  #pragma unroll
  for (int c = 0; c < 5; ++c) out[b * 5 + c] = acc[c];
}

extern "C" void kernel_launch(void* const* d_in, const int* in_sizes, int n_in,
                              void* d_out, int out_size, void* d_ws, size_t ws_size,
                              hipStream_t stream)
{
  const int*   x     = (const int*)d_in[0];
  const float* emb   = (const float*)d_in[1];
  const float* W_ih  = (const float*)d_in[2];
  const float* W_hh  = (const float*)d_in[3];
  const float* b_ih  = (const float*)d_in[4];
  const float* b_hh  = (const float*)d_in[5];
  const float* gamma = (const float*)d_in[6];
  const float* beta  = (const float*)d_in[7];
  const float* W_fc  = (const float*)d_in[8];
  const float* b_fc  = (const float*)d_in[9];

  char* ws = (char*)d_ws;
  float* hT          = (float*)ws;                       // [64][4096] fp32, 1 MB
  float* scale_shift = (float*)(ws + 1048576);           // [2][64] fp32
  u16*   emb_bf      = (u16*)(ws + 1049088);             // [50257][64] bf16, 6.43 MB
  u16*   wih_hi      = (u16*)(ws + 7481984);             // [64][64] bf16
  u16*   whh_hi      = (u16*)(ws + 7490176);
  u16*   whh_lo      = (u16*)(ws + 7498368);             // end ~7.5 MB

  const int emb_n4 = 50257 * 64 / 4;                     // 804112
  cvt_emb_kernel<<<dim3((emb_n4 + 255) / 256), dim3(256), 0, stream>>>(
      (const float4*)emb, (u16x4*)emb_bf, emb_n4);
  cvt_w_kernel<<<dim3(16), dim3(256), 0, stream>>>(
      W_ih, W_hh, wih_hi, whh_hi, whh_lo);
  rnn_scan_kernel<<<dim3(BATCH / 16), dim3(256), 0, stream>>>(
      x, emb_bf, wih_hi, whh_hi, whh_lo, b_ih, b_hh, hT);
  bn_stats_kernel<<<dim3(HID), dim3(256), 0, stream>>>(hT, gamma, beta, scale_shift);
  head_kernel<<<dim3(BATCH / 256), dim3(256), 0, stream>>>(
      hT, scale_shift, W_fc, b_fc, (float*)d_out);
}

// Round 3
// 277.263 us; speedup vs baseline: 1.4269x; 1.4269x over previous
//
#include <hip/hip_runtime.h>

typedef unsigned short u16;
typedef __attribute__((ext_vector_type(8))) short bf16x8;
typedef __attribute__((ext_vector_type(4))) float f32x4;
typedef __attribute__((ext_vector_type(4))) u16 u16x4;

constexpr int BATCH = 4096;
constexpr int SEQ   = 512;
constexpr int HID   = 64;

__device__ __forceinline__ float bf2f(u16 u) {
  union { unsigned int i; float f; } c; c.i = ((unsigned int)u) << 16; return c.f;
}
__device__ __forceinline__ u16 f2bf(float f) {
  union { float f; unsigned int i; } c; c.f = f;
  unsigned int u = c.i;
  u += 0x7fffu + ((u >> 16) & 1u);   // RNE (finite inputs only)
  return (u16)(u >> 16);
}

#define MFMA16(a, b, c) __builtin_amdgcn_mfma_f32_16x16x32_bf16(a, b, c, 0, 0, 0)

// ---- Prep A: fp32 emb -> bf16(hi) table in ws. 4 elems/thread.
__global__ __launch_bounds__(256) void cvt_emb_kernel(
    const float4* __restrict__ src, u16x4* __restrict__ dst, int n4)
{
  int i = blockIdx.x * 256 + threadIdx.x;
  if (i < n4) {
    float4 v = src[i];
    u16x4 o;
    o.x = f2bf(v.x); o.y = f2bf(v.y); o.z = f2bf(v.z); o.w = f2bf(v.w);
    dst[i] = o;
  }
}

// ---- Prep B: W_ih -> hi; W_hh -> hi + lo residual (bf16 pair ~ fp32).
__global__ __launch_bounds__(256) void cvt_w_kernel(
    const float* __restrict__ Wih, const float* __restrict__ Whh,
    u16* __restrict__ wih_hi, u16* __restrict__ whh_hi, u16* __restrict__ whh_lo)
{
  int i = blockIdx.x * 256 + threadIdx.x;   // 0..4095
  wih_hi[i] = f2bf(Wih[i]);
  float w = Whh[i];
  u16 hi = f2bf(w);
  whh_hi[i] = hi;
  whh_lo[i] = f2bf(w - bf2f(hi));
}

// ---- Kernel 1: fused embedding-gather + input projection + tanh-RNN scan.
// 256 blocks x 256 threads; block owns 16 batch rows; wave w owns feats [16w,16w+16).
// Barrier = raw "s_waitcnt lgkmcnt(0); s_barrier" (no vmcnt drain -> emb prefetch
// loads stay in flight across steps). h as bf16 hi+lo pair in swizzled dbuf LDS.
__global__ __launch_bounds__(256) void rnn_scan_kernel(
    const int* __restrict__ xx, const u16* __restrict__ emb_bf,
    const u16* __restrict__ wih_hi, const u16* __restrict__ whh_hi,
    const u16* __restrict__ whh_lo,
    const float* __restrict__ b_ih, const float* __restrict__ b_hh,
    float* __restrict__ hT /* [HID][BATCH] */)
{
  __shared__ u16 hbuf[2 * 2048];   // [buf][hi/lo][m=16][chunk=8][elem=8] = 8 KB
  const int tid = threadIdx.x;
  const int w = tid >> 6;
  const int L = tid & 63;
  const int n = L & 15;
  const int q = L >> 4;
  const int R0 = blockIdx.x << 4;
  const int row  = R0 + n;
  const int feat = (w << 4) + n;

  // h0 = 0: zero buffer 0 (both planes, 4096 B) so step 0 runs the uniform body.
  ((int4*)hbuf)[tid] = int4{0, 0, 0, 0};

  // Constant B-fragments (weights) in registers.
  bf16x8 Bih0 = *(const bf16x8*)(wih_hi + feat * 64 +      8 * q);
  bf16x8 Bih1 = *(const bf16x8*)(wih_hi + feat * 64 + 32 + 8 * q);
  bf16x8 Bh0  = *(const bf16x8*)(whh_hi + feat * 64 +      8 * q);
  bf16x8 Bh1  = *(const bf16x8*)(whh_hi + feat * 64 + 32 + 8 * q);
  bf16x8 Bl0  = *(const bf16x8*)(whh_lo + feat * 64 +      8 * q);
  bf16x8 Bl1  = *(const bf16x8*)(whh_lo + feat * 64 + 32 + 8 * q);
  const float bias = b_ih[feat] + b_hh[feat];

  // LDS A-frag read offsets: row m=n, chunk XOR-swizzled by m&7 (conflict-free).
  const int r0off = n * 64 + (((0 + q) ^ (n & 7)) << 3);
  const int r1off = n * 64 + (((4 + q) ^ (n & 7)) << 3);
  const int cwbase = (w << 1) + (n >> 3);

  // idx prefetch: int4 = 4 steps; K0=[4t..4t+3], K1=[4t+4..4t+7], K2 in flight.
  const int4* x4 = (const int4*)(xx + row * SEQ);
  int4 K0 = x4[0];
  int4 K1 = x4[1];

  // emb prefetch, distance 2: slot p = s&1.
  bf16x8 e0[2], e1[2];
  {
    const u16* eb = emb_bf + (long)K0.x * 64 + 8 * q;
    e0[0] = *(const bf16x8*)(eb);
    e1[0] = *(const bf16x8*)(eb + 32);
    eb = emb_bf + (long)K0.y * 64 + 8 * q;
    e0[1] = *(const bf16x8*)(eb);
    e1[1] = *(const bf16x8*)(eb + 32);
  }

  __syncthreads();   // zero-init visible (full barrier once)

  for (int t = 0; t < SEQ / 4; ++t) {
    const int tt = (t + 2 < SEQ / 4) ? t + 2 : SEQ / 4 - 1;   // clamped (values unused past end)
    int4 K2 = x4[tt];
    const int nid[4] = {K0.z, K0.w, K1.x, K1.y};   // idx for s+2, u=0..3

    #pragma unroll
    for (int u = 0; u < 4; ++u) {
      const int p = u & 1;                 // = s&1
      // LDS h fragments first (critical path: gated by barrier)
      const u16* hb = hbuf + p * 2048;
      bf16x8 ah0 = *(const bf16x8*)(hb + r0off);
      bf16x8 ah1 = *(const bf16x8*)(hb + r1off);
      bf16x8 al0 = *(const bf16x8*)(hb + 1024 + r0off);
      bf16x8 al1 = *(const bf16x8*)(hb + 1024 + r1off);

      // emb MFMAs (independent of LDS -> overlap ds_read latency)
      f32x4 C1 = {bias, bias, bias, bias};
      C1 = MFMA16(e0[p], Bih0, C1);
      C1 = MFMA16(e1[p], Bih1, C1);

      // issue prefetch for s+2 into the just-consumed slot
      {
        const u16* eb = emb_bf + (long)nid[u] * 64 + 8 * q;
        e0[p] = *(const bf16x8*)(eb);
        e1[p] = *(const bf16x8*)(eb + 32);
      }

      // h @ W_hh^T: hi*Whi + lo*Whi + hi*Wlo across 3 accs (dep depth <= 2)
      f32x4 Cx = {0.f, 0.f, 0.f, 0.f};
      f32x4 Cy = {0.f, 0.f, 0.f, 0.f};
      f32x4 Cz = {0.f, 0.f, 0.f, 0.f};
      Cx = MFMA16(ah0, Bh0, Cx);  Cx = MFMA16(al0, Bh0, Cx);
      Cy = MFMA16(ah1, Bh1, Cy);  Cy = MFMA16(al1, Bh1, Cy);
      Cz = MFMA16(ah0, Bl0, Cz);  Cz = MFMA16(ah1, Bl1, Cz);

      u16* wb = hbuf + (p ^ 1) * 2048;
      const bool last = (t == SEQ / 4 - 1) && (u == 3);
      #pragma unroll
      for (int r = 0; r < 4; ++r) {
        float v = C1[r] + ((Cx[r] + Cy[r]) + Cz[r]);
        float ex = __expf(v + v);
        float th = fmaf(-2.0f, __builtin_amdgcn_rcpf(ex + 1.0f), 1.0f);
        const int mw = (q << 2) + r;
        const int off = mw * 64 + ((cwbase ^ (mw & 7)) << 3) + (n & 7);
        // truncated hi/lo split (lo catches the truncation error)
        unsigned int tb = __float_as_uint(th);
        u16 hi = (u16)(tb >> 16);
        float rem = th - __uint_as_float(tb & 0xffff0000u);
        wb[off] = hi;
        wb[1024 + off] = (u16)(__float_as_uint(rem) >> 16);
        if (last) hT[feat * BATCH + R0 + mw] = th;
      }
      // LDS-only barrier: lgkmcnt(0) for ds visibility, vmcnt untouched so the
      // emb prefetch stays outstanding across the step boundary.
      asm volatile("s_waitcnt lgkmcnt(0)\n\ts_barrier" ::: "memory");
    }
    K0 = K1; K1 = K2;
  }
}

// ---- Kernel 2: per-feature batch stats -> folded BN scale/shift (fp32).
__global__ __launch_bounds__(256) void bn_stats_kernel(
    const float* __restrict__ hT, const float* __restrict__ gamma,
    const float* __restrict__ beta, float* __restrict__ scale_shift)
{
  const int j = blockIdx.x;
  const float* v = hT + j * BATCH;
  float sum = 0.f, sq = 0.f;
  for (int i = threadIdx.x; i < BATCH; i += 256) {
    float t = v[i];
    sum += t;
    sq = fmaf(t, t, sq);
  }
  #pragma unroll
  for (int o = 32; o > 0; o >>= 1) {
    sum += __shfl_down(sum, o, 64);
    sq  += __shfl_down(sq,  o, 64);
  }
  __shared__ float s1[4], s2[4];
  const int wv = threadIdx.x >> 6;
  if ((threadIdx.x & 63) == 0) { s1[wv] = sum; s2[wv] = sq; }
  __syncthreads();
  if (threadIdx.x == 0) {
    float S1 = s1[0] + s1[1] + s1[2] + s1[3];
    float S2 = s2[0] + s2[1] + s2[2] + s2[3];
    float mean = S1 * (1.0f / BATCH);
    float var  = S2 * (1.0f / BATCH) - mean * mean;   // biased, matches reference
    float inv  = rsqrtf(var + 1e-5f);
    float sc   = gamma[j] * inv;
    scale_shift[j]      = sc;
    scale_shift[64 + j] = beta[j] - mean * sc;
  }
}

// ---- Kernel 3: logits = (h*scale + shift) @ W_fc^T + b_fc. fp32 out.
__global__ __launch_bounds__(256) void head_kernel(
    const float* __restrict__ hT, const float* __restrict__ scale_shift,
    const float* __restrict__ Wfc, const float* __restrict__ bfc,
    float* __restrict__ out)
{
  const int b = blockIdx.x * 256 + threadIdx.x;
  float acc[5];
  #pragma unroll
  for (int c = 0; c < 5; ++c) acc[c] = bfc[c];
  for (int j = 0; j < HID; ++j) {
    float hv  = hT[j * BATCH + b];
    float hat = fmaf(hv, scale_shift[j], scale_shift[64 + j]);
    #pragma unroll
    for (int c = 0; c < 5; ++c) acc[c] = fmaf(hat, Wfc[c * 64 + j], acc[c]);
  }
  #pragma unroll
  for (int c = 0; c < 5; ++c) out[b * 5 + c] = acc[c];
}

extern "C" void kernel_launch(void* const* d_in, const int* in_sizes, int n_in,
                              void* d_out, int out_size, void* d_ws, size_t ws_size,
                              hipStream_t stream)
{
  const int*   x     = (const int*)d_in[0];
  const float* emb   = (const float*)d_in[1];
  const float* W_ih  = (const float*)d_in[2];
  const float* W_hh  = (const float*)d_in[3];
  const float* b_ih  = (const float*)d_in[4];
  const float* b_hh  = (const float*)d_in[5];
  const float* gamma = (const float*)d_in[6];
  const float* beta  = (const float*)d_in[7];
  const float* W_fc  = (const float*)d_in[8];
  const float* b_fc  = (const float*)d_in[9];

  char* ws = (char*)d_ws;
  float* hT          = (float*)ws;                       // [64][4096] fp32, 1 MB
  float* scale_shift = (float*)(ws + 1048576);           // [2][64] fp32
  u16*   emb_bf      = (u16*)(ws + 1049088);             // [50257][64] bf16, 6.43 MB
  u16*   wih_hi      = (u16*)(ws + 7481984);
  u16*   whh_hi      = (u16*)(ws + 7490176);
  u16*   whh_lo      = (u16*)(ws + 7498368);

  const int emb_n4 = 50257 * 64 / 4;
  cvt_emb_kernel<<<dim3((emb_n4 + 255) / 256), dim3(256), 0, stream>>>(
      (const float4*)emb, (u16x4*)emb_bf, emb_n4);
  cvt_w_kernel<<<dim3(16), dim3(256), 0, stream>>>(
      W_ih, W_hh, wih_hi, whh_hi, whh_lo);
  rnn_scan_kernel<<<dim3(BATCH / 16), dim3(256), 0, stream>>>(
      x, emb_bf, wih_hi, whh_hi, whh_lo, b_ih, b_hh, hT);
  bn_stats_kernel<<<dim3(HID), dim3(256), 0, stream>>>(hT, gamma, beta, scale_shift);
  head_kernel<<<dim3(BATCH / 256), dim3(256), 0, stream>>>(
      hT, scale_shift, W_fc, b_fc, (float*)d_out);
}

// Round 4
// 250.704 us; speedup vs baseline: 1.5780x; 1.1059x over previous
//
#include <hip/hip_runtime.h>

typedef unsigned short u16;
typedef __attribute__((ext_vector_type(8))) short bf16x8;
typedef __attribute__((ext_vector_type(4))) float f32x4;
typedef __attribute__((ext_vector_type(4))) u16 u16x4;

constexpr int BATCH  = 4096;
constexpr int SEQ    = 512;
constexpr int HID    = 64;
constexpr int EMB_N4 = 50257 * 64 / 4;   // 804112 float4 groups in emb

__device__ __forceinline__ float bf2f(u16 u) {
  union { unsigned int i; float f; } c; c.i = ((unsigned int)u) << 16; return c.f;
}
__device__ __forceinline__ u16 f2bf(float f) {
  union { float f; unsigned int i; } c; c.f = f;
  unsigned int u = c.i;
  u += 0x7fffu + ((u >> 16) & 1u);   // RNE (finite inputs only)
  return (u16)(u >> 16);
}

#define MFMA16(a, b, c) __builtin_amdgcn_mfma_f32_16x16x32_bf16(a, b, c, 0, 0, 0)

// ---- Prep (one kernel): emb fp32 -> bf16; W_ih -> hi; W_hh -> hi+lo; zero BN acc.
__global__ __launch_bounds__(256) void prep_kernel(
    const float4* __restrict__ emb4, const float* __restrict__ Wih,
    const float* __restrict__ Whh, u16x4* __restrict__ emb_bf4,
    u16* __restrict__ wih_hi, u16* __restrict__ whh_hi, u16* __restrict__ whh_lo,
    float* __restrict__ bn_acc)
{
  int gid = blockIdx.x * 256 + threadIdx.x;
  if (gid < EMB_N4) {
    float4 v = emb4[gid];
    u16x4 o;
    o.x = f2bf(v.x); o.y = f2bf(v.y); o.z = f2bf(v.z); o.w = f2bf(v.w);
    emb_bf4[gid] = o;
  } else if (gid < EMB_N4 + 1024) {
    int i0 = (gid - EMB_N4) * 4;
    #pragma unroll
    for (int k = 0; k < 4; ++k) {
      int i = i0 + k;
      wih_hi[i] = f2bf(Wih[i]);
      float w = Whh[i];
      u16 hi = f2bf(w);
      whh_hi[i] = hi;
      whh_lo[i] = f2bf(w - bf2f(hi));
    }
  } else if (gid < EMB_N4 + 1024 + 128) {
    bn_acc[gid - (EMB_N4 + 1024)] = 0.f;   // ws is poisoned 0xAA every call
  }
}

// ---- Kernel 1: fused embedding-gather + input projection + tanh-RNN scan.
// 256 blocks x 256 threads; block owns 16 batch rows; wave w owns feats [16w,16w+16).
// Barrier = raw "s_waitcnt lgkmcnt(0); s_barrier": LDS visibility only, emb
// prefetch (distance FOUR steps, rotating 4-slot register buffer) stays in
// flight across barriers -> covers ~900-cyc HBM-miss latency on emb gathers.
// h carried as bf16 hi+lo pair in XOR-swizzled double-buffered LDS.
__global__ __launch_bounds__(256, 1) void rnn_scan_kernel(
    const int* __restrict__ xx, const u16* __restrict__ emb_bf,
    const u16* __restrict__ wih_hi, const u16* __restrict__ whh_hi,
    const u16* __restrict__ whh_lo,
    const float* __restrict__ b_ih, const float* __restrict__ b_hh,
    float* __restrict__ hT /* [HID][BATCH] */, float* __restrict__ bn_acc)
{
  __shared__ u16 hbuf[2 * 2048];   // [buf][hi/lo][m=16][chunk=8][elem=8] = 8 KB
  const int tid = threadIdx.x;
  const int w = tid >> 6;
  const int L = tid & 63;
  const int n = L & 15;
  const int q = L >> 4;
  const int R0 = blockIdx.x << 4;
  const int row  = R0 + n;
  const int feat = (w << 4) + n;

  // h0 = 0: zero buffer 0 (both planes) so step 0 runs the uniform body.
  ((int4*)hbuf)[tid] = int4{0, 0, 0, 0};

  // Constant B-fragments (weights) in registers.
  bf16x8 Bih0 = *(const bf16x8*)(wih_hi + feat * 64 +      8 * q);
  bf16x8 Bih1 = *(const bf16x8*)(wih_hi + feat * 64 + 32 + 8 * q);
  bf16x8 Bh0  = *(const bf16x8*)(whh_hi + feat * 64 +      8 * q);
  bf16x8 Bh1  = *(const bf16x8*)(whh_hi + feat * 64 + 32 + 8 * q);
  bf16x8 Bl0  = *(const bf16x8*)(whh_lo + feat * 64 +      8 * q);
  bf16x8 Bl1  = *(const bf16x8*)(whh_lo + feat * 64 + 32 + 8 * q);
  const float bias = b_ih[feat] + b_hh[feat];

  // LDS A-frag read offsets: row m=n, chunk XOR-swizzled by m&7 (conflict-free).
  const int r0off = n * 64 + (((0 + q) ^ (n & 7)) << 3);
  const int r1off = n * 64 + (((4 + q) ^ (n & 7)) << 3);
  const int cwbase = (w << 1) + (n >> 3);

  // idx stream: int4 = 4 steps. K1 always holds steps 4(t+1)..4(t+1)+3.
  const int4* x4 = (const int4*)(xx + row * SEQ);
  int4 K1 = x4[1];

  // emb prefetch slots: slot u holds step 4t+u's fragments (distance 4).
  bf16x8 e0[4], e1[4];
  {
    int4 K0 = x4[0];
    const int id0[4] = {K0.x, K0.y, K0.z, K0.w};
    #pragma unroll
    for (int u = 0; u < 4; ++u) {
      const u16* eb = emb_bf + (long)id0[u] * 64 + 8 * q;
      e0[u] = *(const bf16x8*)(eb);
      e1[u] = *(const bf16x8*)(eb + 32);
    }
  }

  __syncthreads();   // zero-init visible (full barrier once)

  for (int t = 0; t < SEQ / 4; ++t) {
    int4 K2 = x4[(t + 2 < SEQ / 4) ? t + 2 : SEQ / 4 - 1];  // clamped; dup loads harmless
    const int nid[4] = {K1.x, K1.y, K1.z, K1.w};            // idx for steps 4t+4+u
    const bool lastt = (t == SEQ / 4 - 1);

    #pragma unroll
    for (int u = 0; u < 4; ++u) {
      const int p = u & 1;                 // LDS buffer parity = s&1
      // LDS h fragments first (critical path: gated by barrier)
      const u16* hb = hbuf + p * 2048;
      bf16x8 ah0 = *(const bf16x8*)(hb + r0off);
      bf16x8 ah1 = *(const bf16x8*)(hb + r1off);
      bf16x8 al0 = *(const bf16x8*)(hb + 1024 + r0off);
      bf16x8 al1 = *(const bf16x8*)(hb + 1024 + r1off);

      // emb MFMAs (independent of LDS -> overlap ds_read latency)
      f32x4 C1 = {bias, bias, bias, bias};
      C1 = MFMA16(e0[u], Bih0, C1);
      C1 = MFMA16(e1[u], Bih1, C1);

      // refill slot u with step s+4 (stays in flight across 4 barriers)
      {
        const u16* eb = emb_bf + (long)nid[u] * 64 + 8 * q;
        e0[u] = *(const bf16x8*)(eb);
        e1[u] = *(const bf16x8*)(eb + 32);
      }

      // h @ W_hh^T: hi*Whi + lo*Whi + hi*Wlo across 3 accs (dep depth <= 2)
      f32x4 Cx = {0.f, 0.f, 0.f, 0.f};
      f32x4 Cy = {0.f, 0.f, 0.f, 0.f};
      f32x4 Cz = {0.f, 0.f, 0.f, 0.f};
      Cx = MFMA16(ah0, Bh0, Cx);  Cx = MFMA16(al0, Bh0, Cx);
      Cy = MFMA16(ah1, Bh1, Cy);  Cy = MFMA16(al1, Bh1, Cy);
      Cz = MFMA16(ah0, Bl0, Cz);  Cz = MFMA16(ah1, Bl1, Cz);

      u16* wb = hbuf + (p ^ 1) * 2048;
      float th4[4];
      #pragma unroll
      for (int r = 0; r < 4; ++r) {
        float v = (C1[r] + Cx[r]) + (Cy[r] + Cz[r]);
        // tanh(v) = 1 - 2/(1 + 2^(2*log2e*v)); exact saturation at +-1
        float ex = __builtin_amdgcn_exp2f(2.8853900817779268f * v);
        float th = fmaf(-2.0f, __builtin_amdgcn_rcpf(ex + 1.0f), 1.0f);
        th4[r] = th;
        const int mw = (q << 2) + r;
        const int off = mw * 64 + ((cwbase ^ (mw & 7)) << 3) + (n & 7);
        // truncated hi/lo split (lo catches the truncation error exactly)
        unsigned int tb = __float_as_uint(th);
        wb[off] = (u16)(tb >> 16);
        wb[1024 + off] = (u16)(__float_as_uint(th - __uint_as_float(tb & 0xffff0000u)) >> 16);
      }

      if (u == 3 && lastt) {   // epilogue: h_n out + BN partial sums (off hot path)
        float s1 = 0.f, s2 = 0.f;
        #pragma unroll
        for (int r = 0; r < 4; ++r) {
          hT[feat * BATCH + R0 + (q << 2) + r] = th4[r];
          s1 += th4[r];
          s2 = fmaf(th4[r], th4[r], s2);
        }
        s1 += __shfl_xor(s1, 16, 64);  s2 += __shfl_xor(s2, 16, 64);
        s1 += __shfl_xor(s1, 32, 64);  s2 += __shfl_xor(s2, 32, 64);
        if (q == 0) {
          atomicAdd(bn_acc + feat, s1);
          atomicAdd(bn_acc + 64 + feat, s2);
        }
      }

      // LDS-only barrier: lgkmcnt(0) for ds visibility; vmcnt untouched so the
      // 4-deep emb prefetch stays outstanding across step boundaries.
      asm volatile("s_waitcnt lgkmcnt(0)\n\ts_barrier" ::: "memory");
    }
    K1 = K2;
  }
}

// ---- Kernel 2: BN fold (from accumulated sums) + logits GEMV. fp32 out.
__global__ __launch_bounds__(256) void head_kernel(
    const float* __restrict__ hT, const float* __restrict__ bn_acc,
    const float* __restrict__ gamma, const float* __restrict__ beta,
    const float* __restrict__ Wfc, const float* __restrict__ bfc,
    float* __restrict__ out)
{
  __shared__ float sc[64], sh[64];
  const int tid = threadIdx.x;
  if (tid < 64) {
    float mean = bn_acc[tid] * (1.0f / BATCH);
    float var  = bn_acc[64 + tid] * (1.0f / BATCH) - mean * mean;  // biased
    float inv  = rsqrtf(var + 1e-5f);
    float s    = gamma[tid] * inv;
    sc[tid] = s;
    sh[tid] = beta[tid] - mean * s;
  }
  __syncthreads();
  const int b = blockIdx.x * 256 + tid;
  float acc[5];
  #pragma unroll
  for (int c = 0; c < 5; ++c) acc[c] = bfc[c];
  for (int j = 0; j < HID; ++j) {
    float hv  = hT[j * BATCH + b];                 // coalesced across lanes
    float hat = fmaf(hv, sc[j], sh[j]);
    #pragma unroll
    for (int c = 0; c < 5; ++c) acc[c] = fmaf(hat, Wfc[c * 64 + j], acc[c]);
  }
  #pragma unroll
  for (int c = 0; c < 5; ++c) out[b * 5 + c] = acc[c];
}

extern "C" void kernel_launch(void* const* d_in, const int* in_sizes, int n_in,
                              void* d_out, int out_size, void* d_ws, size_t ws_size,
                              hipStream_t stream)
{
  const int*   x     = (const int*)d_in[0];
  const float* emb   = (const float*)d_in[1];
  const float* W_ih  = (const float*)d_in[2];
  const float* W_hh  = (const float*)d_in[3];
  const float* b_ih  = (const float*)d_in[4];
  const float* b_hh  = (const float*)d_in[5];
  const float* gamma = (const float*)d_in[6];
  const float* beta  = (const float*)d_in[7];
  const float* W_fc  = (const float*)d_in[8];
  const float* b_fc  = (const float*)d_in[9];

  char* ws = (char*)d_ws;
  float* hT     = (float*)ws;                 // [64][4096] fp32, 1 MB
  float* bn_acc = (float*)(ws + 1048576);     // [2][64] fp32 atomics
  u16*   emb_bf = (u16*)(ws + 1049088);       // [50257][64] bf16, 6.43 MB
  u16*   wih_hi = (u16*)(ws + 7481984);
  u16*   whh_hi = (u16*)(ws + 7490176);
  u16*   whh_lo = (u16*)(ws + 7498368);

  const int prep_items = EMB_N4 + 1024 + 128;
  prep_kernel<<<dim3((prep_items + 255) / 256), dim3(256), 0, stream>>>(
      (const float4*)emb, W_ih, W_hh, (u16x4*)emb_bf, wih_hi, whh_hi, whh_lo, bn_acc);
  rnn_scan_kernel<<<dim3(BATCH / 16), dim3(256), 0, stream>>>(
      x, emb_bf, wih_hi, whh_hi, whh_lo, b_ih, b_hh, hT, bn_acc);
  head_kernel<<<dim3(BATCH / 256), dim3(256), 0, stream>>>(
      hT, bn_acc, gamma, beta, W_fc, b_fc, (float*)d_out);
}